// Round 3
// baseline (585.078 us; speedup 1.0000x reference)
//
#include <hip/hip_runtime.h>

#define NB 8
#define NS 2048
#define NH 768
#define NPOS (NB*NS)

typedef short short8 __attribute__((ext_vector_type(8)));
typedef float floatx4 __attribute__((ext_vector_type(4)));

// pack two fp32's bf16-truncations into one dword: low short = hi(b0), high short = hi(b1)
__device__ __forceinline__ unsigned pack_bf16(unsigned b0, unsigned b1) {
  return __builtin_amdgcn_perm(b1, b0, 0x07060302u);
}

// ---------------- Kernel A: build V = U * diag((-i)^popcount(j)) ----------------
__global__ void build_V_kernel(const float* __restrict__ wts,
                               float* __restrict__ Vre, float* __restrict__ Vim) {
  int j = threadIdx.x;
  if (j >= 16) return;
  float ar[16], ai[16];
#pragma unroll
  for (int i = 0; i < 16; i++) { ar[i] = (i == j) ? 1.f : 0.f; ai[i] = 0.f; }
#pragma unroll
  for (int l = 0; l < 2; l++) {
#pragma unroll
    for (int q = 0; q < 4; q++) {
      float phi = wts[(l*4+q)*3+0];
      float th  = wts[(l*4+q)*3+1];
      float om  = wts[(l*4+q)*3+2];
      float ct = cosf(0.5f*th), st = sinf(0.5f*th);
      float sm = 0.5f*(phi+om), df = 0.5f*(phi-om);
      float cs = cosf(sm), ss = sinf(sm), cd = cosf(df), sd = sinf(df);
      float Ar =  cs*ct, Ai = -ss*ct;
      float Br = -cd*st, Bi = -sd*st;
      float Cr =  cd*st, Ci = -sd*st;
      float Dr =  cs*ct, Di =  ss*ct;
      int pb = 1 << (3-q);
#pragma unroll
      for (int b0 = 0; b0 < 16; b0++) {
        if (b0 & pb) continue;
        int b1 = b0 | pb;
        float xr = ar[b0], xi = ai[b0], yr = ar[b1], yi = ai[b1];
        ar[b0] = Ar*xr - Ai*xi + Br*yr - Bi*yi;
        ai[b0] = Ar*xi + Ai*xr + Br*yi + Bi*yr;
        ar[b1] = Cr*xr - Ci*xi + Dr*yr - Di*yi;
        ai[b1] = Cr*xi + Ci*xr + Dr*yi + Di*yr;
      }
    }
    const int r = (l == 0) ? 1 : 2;
#pragma unroll
    for (int i2 = 0; i2 < 4; i2++) {
      int cb = 1 << (3-i2);
      int tb = 1 << (3-((i2+r)&3));
#pragma unroll
      for (int b0 = 0; b0 < 16; b0++) {
        if ((b0 & cb) && !(b0 & tb)) {
          int b1 = b0 | tb;
          float tr = ar[b0], ti = ai[b0];
          ar[b0] = ar[b1]; ai[b0] = ai[b1];
          ar[b1] = tr;     ai[b1] = ti;
        }
      }
    }
  }
  int pc = __popc((unsigned)j) & 3;
#pragma unroll
  for (int i = 0; i < 16; i++) {
    float vr = ar[i], vi = ai[i], orr, oi;
    if      (pc == 0) { orr =  vr; oi =  vi; }
    else if (pc == 1) { orr =  vi; oi = -vr; }
    else if (pc == 2) { orr = -vr; oi = -vi; }
    else              { orr = -vi; oi =  vr; }
    Vre[i*16+j] = orr;
    Vim[i*16+j] = oi;
  }
}

// ---------------- Kernel B: Q/K projection + VQC evaluation ----------------
// Wq/Wk staged as separate [768][4] LDS arrays: 16B rows -> 8 consecutive e
// cover all 32 banks -> conflict-free ds_read_b128.
__global__ __launch_bounds__(256) void proj_vqc_kernel(
    const float* __restrict__ E, const float* __restrict__ Wq, const float* __restrict__ bq,
    const float* __restrict__ Wk, const float* __restrict__ bk,
    const float* __restrict__ Vre, const float* __restrict__ Vim,
    float* __restrict__ Qv, float* __restrict__ Kv) {
  __shared__ __align__(16) float WqL[768*4];
  __shared__ __align__(16) float WkL[768*4];
  __shared__ float Vsh[2][16*17];
  int tid = threadIdx.x;
  for (int idx = tid; idx < 768*4; idx += 256) {
    int e = idx >> 2, w = idx & 3;
    WqL[e*4+w] = Wq[w*768+e];
    WkL[e*4+w] = Wk[w*768+e];
  }
  if (tid < 256) {
    int i = tid >> 4, jj = tid & 15;
    Vsh[0][i*17+jj] = Vre[tid];
    Vsh[1][i*17+jj] = Vim[tid];
  }
  __syncthreads();
  float bqr0=bq[0], bqr1=bq[1], bqr2=bq[2], bqr3=bq[3];
  float bkr0=bk[0], bkr1=bk[1], bkr2=bk[2], bkr3=bk[3];
  int lane = tid & 63;
  int wid  = blockIdx.x*4 + (tid >> 6);
  int nw   = gridDim.x*4;
  int grp  = lane >> 4;
  int i    = lane & 15;
  for (int pos = wid; pos < NPOS; pos += nw) {
    const float* er = E + (size_t)pos*768;
    float pq[4] = {0.f,0.f,0.f,0.f};
    float pk[4] = {0.f,0.f,0.f,0.f};
#pragma unroll
    for (int k2 = 0; k2 < 3; k2++) {
      float4 ev = *(const float4*)(er + lane*4 + 256*k2);
#pragma unroll
      for (int jj = 0; jj < 4; jj++) {
        int e = lane*4 + 256*k2 + jj;
        float evs = (jj==0) ? ev.x : (jj==1) ? ev.y : (jj==2) ? ev.z : ev.w;
        float4 wq4 = *(const float4*)&WqL[e*4];
        float4 wk4 = *(const float4*)&WkL[e*4];
        pq[0] += evs*wq4.x; pq[1] += evs*wq4.y; pq[2] += evs*wq4.z; pq[3] += evs*wq4.w;
        pk[0] += evs*wk4.x; pk[1] += evs*wk4.y; pk[2] += evs*wk4.z; pk[3] += evs*wk4.w;
      }
    }
    float part[8];
#pragma unroll
    for (int w = 0; w < 8; w++) {
      float v = (w < 4) ? pq[w] : pk[w-4];
      v += __shfl_xor(v, 32); v += __shfl_xor(v, 16); v += __shfl_xor(v, 8);
      v += __shfl_xor(v, 4);  v += __shfl_xor(v, 2);  v += __shfl_xor(v, 1);
      part[w] = v;
    }
    if (grp < 2) {
      float a0,a1,a2,a3;
      if (grp == 0) { a0=part[0]+bqr0; a1=part[1]+bqr1; a2=part[2]+bqr2; a3=part[3]+bqr3; }
      else          { a0=part[4]+bkr0; a1=part[5]+bkr1; a2=part[6]+bkr2; a3=part[7]+bkr3; }
      float c0=cosf(0.5f*a0), s0=sinf(0.5f*a0);
      float c1=cosf(0.5f*a1), s1=sinf(0.5f*a1);
      float c2=cosf(0.5f*a2), s2=sinf(0.5f*a2);
      float c3=cosf(0.5f*a3), s3=sinf(0.5f*a3);
      float m[16];
#pragma unroll
      for (int j2 = 0; j2 < 16; j2++) {
        float f0 = (j2 & 8) ? s0 : c0;
        float f1 = (j2 & 4) ? s1 : c1;
        float f2 = (j2 & 2) ? s2 : c2;
        float f3 = (j2 & 1) ? s3 : c3;
        m[j2] = f0*f1*f2*f3;
      }
      float re = 0.f, im = 0.f;
#pragma unroll
      for (int j2 = 0; j2 < 16; j2++) {
        re += Vsh[0][i*17+j2]*m[j2];
        im += Vsh[1][i*17+j2]*m[j2];
      }
      float pr = re*re + im*im;
      float r0 = (i & 8) ? -pr : pr;
      float r1 = (i & 4) ? -pr : pr;
      float r2 = (i & 2) ? -pr : pr;
      float r3 = (i & 1) ? -pr : pr;
#pragma unroll
      for (int off = 8; off >= 1; off >>= 1) {
        r0 += __shfl_xor(r0, off);
        r1 += __shfl_xor(r1, off);
        r2 += __shfl_xor(r2, off);
        r3 += __shfl_xor(r3, off);
      }
      if (i == 0) {
        float* dst = (grp == 0 ? Qv : Kv) + (size_t)pos*4;
        dst[0]=r0; dst[1]=r1; dst[2]=r2; dst[3]=r3;
      }
    }
  }
}

// ---------------- Kernel C: fused flash attention, split-bf16 MFMA ----------------
// Block tile: 128 s x 128 h, K-chunks of 32 t.
// LDS 16B-chunk XOR swizzle: chunk' = chunk ^ ((row>>1)&3)  -> all staging
// writes and fragment reads spread 8 lanes per 4-bank group (conflict-free).
// E chunk register-prefetched: global loads issued right after the tiles-ready
// barrier, consumed in the NEXT iteration's staging phase.
#define BS 128
#define BH 128
#define TK 32

__device__ __forceinline__ int swz(int row, int chunk) {
  return row*TK + ((chunk ^ ((row>>1)&3))*8);   // in shorts; chunk = 8 shorts = 16B
}

__global__ __launch_bounds__(256, 3) void attn_kernel(
    const float* __restrict__ E, const float* __restrict__ Qv,
    const float* __restrict__ Kv, float* __restrict__ out) {
  int sblk = blockIdx.x;   // 0..15
  int hblk = blockIdx.y;   // 0..5
  int b    = blockIdx.z;   // 0..7
  int tid  = threadIdx.x;
  int lane = tid & 63;
  int w    = tid >> 6;

  __shared__ __align__(16) unsigned short sAhi[BS*TK];
  __shared__ __align__(16) unsigned short sAlo[BS*TK];
  __shared__ __align__(16) unsigned short sBhi[BH*TK];
  __shared__ __align__(16) unsigned short sBlo[BH*TK];
  __shared__ float kvf[2][TK][4];
  __shared__ float denp[BS*4];
  __shared__ float dfin[BS];

  const float* Eb  = E  + (size_t)b*NS*NH + hblk*BH;
  const float* Kvb = Kv + (size_t)b*NS*4;

  int s0_ = tid >> 2, q0_ = tid & 3;
  int s1_ = 64 + s0_;
  floatx4 qv0, qv1;
  {
    const float4 t0 = *(const float4*)&Qv[((size_t)(b*NS + sblk*BS) + s0_)*4];
    const float4 t1 = *(const float4*)&Qv[((size_t)(b*NS + sblk*BS) + s1_)*4];
    qv0 = floatx4{t0.x, t0.y, t0.z, t0.w};
    qv1 = floatx4{t1.x, t1.y, t1.z, t1.w};
  }
  float den0 = 0.f, den1 = 0.f;

  int sh = w & 1, hh = w >> 1;
  floatx4 acc[4][4];
#pragma unroll
  for (int i = 0; i < 4; i++)
#pragma unroll
    for (int jt = 0; jt < 4; jt++) acc[i][jt] = floatx4{0.f,0.f,0.f,0.f};

  // E staging registers: [r2][jp][pair] -> ereg[r2*8 + jp*2 + pair]
  float ereg[16];
  {
#pragma unroll
    for (int r2 = 0; r2 < 2; r2++) {
      int task = tid + 256*r2;
      int q2 = task >> 7, h2 = task & 127;
      const float* p = Eb + (size_t)(q2*8)*NH + h2;
#pragma unroll
      for (int jp = 0; jp < 4; jp++) {
        ereg[r2*8+jp*2  ] = p[(size_t)(2*jp  )*NH];
        ereg[r2*8+jp*2+1] = p[(size_t)(2*jp+1)*NH];
      }
    }
  }
  if (tid < TK*4) kvf[0][tid>>2][tid&3] = Kvb[tid];

  int m16 = lane & 15, q16 = lane >> 4;
  int cidx = (q16 ^ ((m16 >> 1) & 3)) * 8;   // swizzled chunk offset for frag reads

  for (int tc = 0; tc < NS; tc += TK) {
    int cb = (tc / TK) & 1;
    __syncthreads();   // prev MFMA done reading tiles; kv[cb] visible

    if (tc + TK < NS && tid < TK*4)
      kvf[cb^1][tid>>2][tid&3] = Kvb[(size_t)(tc+TK)*4 + tid];

    // --- stage E chunk from ereg -> sB[h][t] hi/lo (swizzled) ---
#pragma unroll
    for (int r2 = 0; r2 < 2; r2++) {
      int task = tid + 256*r2;
      int q2 = task >> 7, h2 = task & 127;
      unsigned hi4[4], lo4[4];
#pragma unroll
      for (int jp = 0; jp < 4; jp++) {
        float ea = ereg[r2*8+jp*2];
        float eb2 = ereg[r2*8+jp*2+1];
        unsigned ba = __float_as_uint(ea), bb = __float_as_uint(eb2);
        unsigned ha = ba & 0xFFFF0000u,  hb2 = bb & 0xFFFF0000u;
        float la = ea - __uint_as_float(ha);
        float lb = eb2 - __uint_as_float(hb2);
        hi4[jp] = pack_bf16(ba, bb);
        lo4[jp] = pack_bf16(__float_as_uint(la), __float_as_uint(lb));
      }
      int off = swz(h2, q2);
      *(uint4*)&sBhi[off] = make_uint4(hi4[0],hi4[1],hi4[2],hi4[3]);
      *(uint4*)&sBlo[off] = make_uint4(lo4[0],lo4[1],lo4[2],lo4[3]);
    }

    // --- P-gen: p = exp(qv.kv), split, write A tile (swizzled) ---
#pragma unroll
    for (int r = 0; r < 2; r++) {
      int s = r ? s1_ : s0_;
      int q = q0_;
      floatx4 qv = r ? qv1 : qv0;
      unsigned hi4[4], lo4[4];
      float dsum = 0.f;
#pragma unroll
      for (int jp = 0; jp < 4; jp++) {
        float4 ka = *(const float4*)&kvf[cb][q*8 + 2*jp][0];
        float4 kb = *(const float4*)&kvf[cb][q*8 + 2*jp + 1][0];
        float arga = qv.x*ka.x + qv.y*ka.y + qv.z*ka.z + qv.w*ka.w;
        float argb = qv.x*kb.x + qv.y*kb.y + qv.z*kb.z + qv.w*kb.w;
        float pa = __expf(arga), pb = __expf(argb);
        dsum += pa + pb;
        unsigned bpa = __float_as_uint(pa), bpb = __float_as_uint(pb);
        unsigned hpa = bpa & 0xFFFF0000u,  hpb = bpb & 0xFFFF0000u;
        float lpa = pa - __uint_as_float(hpa);
        float lpb = pb - __uint_as_float(hpb);
        hi4[jp] = pack_bf16(bpa, bpb);
        lo4[jp] = pack_bf16(__float_as_uint(lpa), __float_as_uint(lpb));
      }
      if (r) den1 += dsum; else den0 += dsum;
      int off = swz(s, q);
      *(uint4*)&sAhi[off] = make_uint4(hi4[0],hi4[1],hi4[2],hi4[3]);
      *(uint4*)&sAlo[off] = make_uint4(lo4[0],lo4[1],lo4[2],lo4[3]);
    }

    __syncthreads();   // tiles ready

    // --- prefetch next E chunk into regs (overlaps MFMA below) ---
    if (tc + TK < NS) {
#pragma unroll
      for (int r2 = 0; r2 < 2; r2++) {
        int task = tid + 256*r2;
        int q2 = task >> 7, h2 = task & 127;
        const float* p = Eb + (size_t)(tc + TK + q2*8)*NH + h2;
#pragma unroll
        for (int jp = 0; jp < 4; jp++) {
          ereg[r2*8+jp*2  ] = p[(size_t)(2*jp  )*NH];
          ereg[r2*8+jp*2+1] = p[(size_t)(2*jp+1)*NH];
        }
      }
    }

    // --- MFMA: wave (sh,hh) computes 64x64 via 4x4 tiles of 16x16x32 ---
    short8 bh_[4], bl_[4];
#pragma unroll
    for (int jt = 0; jt < 4; jt++) {
      int hrow = hh*64 + jt*16 + m16;
      bh_[jt] = __builtin_bit_cast(short8, *(const uint4*)&sBhi[hrow*TK + cidx]);
      bl_[jt] = __builtin_bit_cast(short8, *(const uint4*)&sBlo[hrow*TK + cidx]);
    }
#pragma unroll
    for (int i = 0; i < 4; i++) {
      int srow = sh*64 + i*16 + m16;
      short8 ah = __builtin_bit_cast(short8, *(const uint4*)&sAhi[srow*TK + cidx]);
      short8 al = __builtin_bit_cast(short8, *(const uint4*)&sAlo[srow*TK + cidx]);
#pragma unroll
      for (int jt = 0; jt < 4; jt++) {
        acc[i][jt] = __builtin_amdgcn_mfma_f32_16x16x32_bf16(ah, bl_[jt], acc[i][jt], 0, 0, 0);
        acc[i][jt] = __builtin_amdgcn_mfma_f32_16x16x32_bf16(al, bh_[jt], acc[i][jt], 0, 0, 0);
        acc[i][jt] = __builtin_amdgcn_mfma_f32_16x16x32_bf16(ah, bh_[jt], acc[i][jt], 0, 0, 0);
      }
    }
  }

  // --- denominator reduce ---
  __syncthreads();
  denp[s0_*4 + q0_] = den0;
  denp[s1_*4 + q0_] = den1;
  __syncthreads();
  if (tid < BS) {
    dfin[tid] = denp[tid*4] + denp[tid*4+1] + denp[tid*4+2] + denp[tid*4+3];
  }
  __syncthreads();

  // --- epilogue: C/D layout col=lane&15, row=(lane>>4)*4+reg ---
  float* ob = out + ((size_t)(b*NS + sblk*BS))*NH + hblk*BH;
#pragma unroll
  for (int i = 0; i < 4; i++) {
#pragma unroll
    for (int reg = 0; reg < 4; reg++) {
      int row = q16*4 + reg;
      int s_loc = sh*64 + i*16 + row;
      float invd = 1.0f / dfin[s_loc];
#pragma unroll
      for (int jt = 0; jt < 4; jt++) {
        int h_loc = hh*64 + jt*16 + m16;
        ob[(size_t)s_loc*NH + h_loc] = acc[i][jt][reg] * invd;
      }
    }
  }
}

extern "C" void kernel_launch(void* const* d_in, const int* in_sizes, int n_in,
                              void* d_out, int out_size, void* d_ws, size_t ws_size,
                              hipStream_t stream) {
  const float* E   = (const float*)d_in[0];
  const float* Wq  = (const float*)d_in[1];
  const float* bq  = (const float*)d_in[2];
  const float* Wk  = (const float*)d_in[3];
  const float* bk  = (const float*)d_in[4];
  const float* wts = (const float*)d_in[5];
  float* ws  = (float*)d_ws;
  float* Vre = ws;
  float* Vim = ws + 256;
  float* Qv  = ws + 512;
  float* Kv  = ws + 512 + NPOS*4;
  float* out = (float*)d_out;

  build_V_kernel<<<1, 64, 0, stream>>>(wts, Vre, Vim);
  proj_vqc_kernel<<<1024, 256, 0, stream>>>(E, Wq, bq, Wk, bk, Vre, Vim, Qv, Kv);
  attn_kernel<<<dim3(16, 6, 8), 256, 0, stream>>>(E, Qv, Kv, out);
}

// Round 4
// 323.182 us; speedup vs baseline: 1.8104x; 1.8104x over previous
//
#include <hip/hip_runtime.h>

#define NB 8
#define NS 2048
#define NH 768
#define NPOS (NB*NS)

typedef short short8 __attribute__((ext_vector_type(8)));
typedef float floatx4 __attribute__((ext_vector_type(4)));

// pack bf16-truncations of two fp32 into one dword: low short=hi(b0), high short=hi(b1)
__device__ __forceinline__ unsigned pack_bf16(unsigned b0, unsigned b1) {
  return __builtin_amdgcn_perm(b1, b0, 0x07060302u);
}

// async global->LDS, 16B per lane; LDS dest must be wave-uniform base + lane*16
#define GLOAD_LDS16(gp, lp) __builtin_amdgcn_global_load_lds( \
  (const __attribute__((address_space(1))) unsigned int*)(gp), \
  (__attribute__((address_space(3))) unsigned int*)(lp), 16, 0, 0)

// ---------------- Kernel A: build V = U * diag((-i)^popcount(j)) ----------------
__global__ void build_V_kernel(const float* __restrict__ wts,
                               float* __restrict__ Vre, float* __restrict__ Vim) {
  int j = threadIdx.x;
  if (j >= 16) return;
  float ar[16], ai[16];
#pragma unroll
  for (int i = 0; i < 16; i++) { ar[i] = (i == j) ? 1.f : 0.f; ai[i] = 0.f; }
#pragma unroll
  for (int l = 0; l < 2; l++) {
#pragma unroll
    for (int q = 0; q < 4; q++) {
      float phi = wts[(l*4+q)*3+0];
      float th  = wts[(l*4+q)*3+1];
      float om  = wts[(l*4+q)*3+2];
      float ct = cosf(0.5f*th), st = sinf(0.5f*th);
      float sm = 0.5f*(phi+om), df = 0.5f*(phi-om);
      float cs = cosf(sm), ss = sinf(sm), cd = cosf(df), sd = sinf(df);
      float Ar =  cs*ct, Ai = -ss*ct;
      float Br = -cd*st, Bi = -sd*st;
      float Cr =  cd*st, Ci = -sd*st;
      float Dr =  cs*ct, Di =  ss*ct;
      int pb = 1 << (3-q);
#pragma unroll
      for (int b0 = 0; b0 < 16; b0++) {
        if (b0 & pb) continue;
        int b1 = b0 | pb;
        float xr = ar[b0], xi = ai[b0], yr = ar[b1], yi = ai[b1];
        ar[b0] = Ar*xr - Ai*xi + Br*yr - Bi*yi;
        ai[b0] = Ar*xi + Ai*xr + Br*yi + Bi*yr;
        ar[b1] = Cr*xr - Ci*xi + Dr*yr - Di*yi;
        ai[b1] = Cr*xi + Ci*xr + Dr*yi + Di*yr;
      }
    }
    const int r = (l == 0) ? 1 : 2;
#pragma unroll
    for (int i2 = 0; i2 < 4; i2++) {
      int cb = 1 << (3-i2);
      int tb = 1 << (3-((i2+r)&3));
#pragma unroll
      for (int b0 = 0; b0 < 16; b0++) {
        if ((b0 & cb) && !(b0 & tb)) {
          int b1 = b0 | tb;
          float tr = ar[b0], ti = ai[b0];
          ar[b0] = ar[b1]; ai[b0] = ai[b1];
          ar[b1] = tr;     ai[b1] = ti;
        }
      }
    }
  }
  int pc = __popc((unsigned)j) & 3;
#pragma unroll
  for (int i = 0; i < 16; i++) {
    float vr = ar[i], vi = ai[i], orr, oi;
    if      (pc == 0) { orr =  vr; oi =  vi; }
    else if (pc == 1) { orr =  vi; oi = -vr; }
    else if (pc == 2) { orr = -vr; oi = -vi; }
    else              { orr = -vi; oi =  vr; }
    Vre[i*16+j] = orr;
    Vim[i*16+j] = oi;
  }
}

// ---------------- Kernel B: Q/K projection + VQC evaluation ----------------
__global__ __launch_bounds__(256) void proj_vqc_kernel(
    const float* __restrict__ E, const float* __restrict__ Wq, const float* __restrict__ bq,
    const float* __restrict__ Wk, const float* __restrict__ bk,
    const float* __restrict__ Vre, const float* __restrict__ Vim,
    float* __restrict__ Qv, float* __restrict__ Kv) {
  __shared__ __align__(16) float WqL[768*4];
  __shared__ __align__(16) float WkL[768*4];
  __shared__ float Vsh[2][16*17];
  int tid = threadIdx.x;
  for (int idx = tid; idx < 768*4; idx += 256) {
    int e = idx >> 2, w = idx & 3;
    WqL[e*4+w] = Wq[w*768+e];
    WkL[e*4+w] = Wk[w*768+e];
  }
  if (tid < 256) {
    int i = tid >> 4, jj = tid & 15;
    Vsh[0][i*17+jj] = Vre[tid];
    Vsh[1][i*17+jj] = Vim[tid];
  }
  __syncthreads();
  float bqr0=bq[0], bqr1=bq[1], bqr2=bq[2], bqr3=bq[3];
  float bkr0=bk[0], bkr1=bk[1], bkr2=bk[2], bkr3=bk[3];
  int lane = tid & 63;
  int wid  = blockIdx.x*4 + (tid >> 6);
  int nw   = gridDim.x*4;
  int grp  = lane >> 4;
  int i    = lane & 15;
  for (int pos = wid; pos < NPOS; pos += nw) {
    const float* er = E + (size_t)pos*768;
    float pq[4] = {0.f,0.f,0.f,0.f};
    float pk[4] = {0.f,0.f,0.f,0.f};
#pragma unroll
    for (int k2 = 0; k2 < 3; k2++) {
      float4 ev = *(const float4*)(er + lane*4 + 256*k2);
#pragma unroll
      for (int jj = 0; jj < 4; jj++) {
        int e = lane*4 + 256*k2 + jj;
        float evs = (jj==0) ? ev.x : (jj==1) ? ev.y : (jj==2) ? ev.z : ev.w;
        float4 wq4 = *(const float4*)&WqL[e*4];
        float4 wk4 = *(const float4*)&WkL[e*4];
        pq[0] += evs*wq4.x; pq[1] += evs*wq4.y; pq[2] += evs*wq4.z; pq[3] += evs*wq4.w;
        pk[0] += evs*wk4.x; pk[1] += evs*wk4.y; pk[2] += evs*wk4.z; pk[3] += evs*wk4.w;
      }
    }
    float part[8];
#pragma unroll
    for (int w = 0; w < 8; w++) {
      float v = (w < 4) ? pq[w] : pk[w-4];
      v += __shfl_xor(v, 32); v += __shfl_xor(v, 16); v += __shfl_xor(v, 8);
      v += __shfl_xor(v, 4);  v += __shfl_xor(v, 2);  v += __shfl_xor(v, 1);
      part[w] = v;
    }
    if (grp < 2) {
      float a0,a1,a2,a3;
      if (grp == 0) { a0=part[0]+bqr0; a1=part[1]+bqr1; a2=part[2]+bqr2; a3=part[3]+bqr3; }
      else          { a0=part[4]+bkr0; a1=part[5]+bkr1; a2=part[6]+bkr2; a3=part[7]+bkr3; }
      float c0=cosf(0.5f*a0), s0=sinf(0.5f*a0);
      float c1=cosf(0.5f*a1), s1=sinf(0.5f*a1);
      float c2=cosf(0.5f*a2), s2=sinf(0.5f*a2);
      float c3=cosf(0.5f*a3), s3=sinf(0.5f*a3);
      float m[16];
#pragma unroll
      for (int j2 = 0; j2 < 16; j2++) {
        float f0 = (j2 & 8) ? s0 : c0;
        float f1 = (j2 & 4) ? s1 : c1;
        float f2 = (j2 & 2) ? s2 : c2;
        float f3 = (j2 & 1) ? s3 : c3;
        m[j2] = f0*f1*f2*f3;
      }
      float re = 0.f, im = 0.f;
#pragma unroll
      for (int j2 = 0; j2 < 16; j2++) {
        re += Vsh[0][i*17+j2]*m[j2];
        im += Vsh[1][i*17+j2]*m[j2];
      }
      float pr = re*re + im*im;
      float r0 = (i & 8) ? -pr : pr;
      float r1 = (i & 4) ? -pr : pr;
      float r2 = (i & 2) ? -pr : pr;
      float r3 = (i & 1) ? -pr : pr;
#pragma unroll
      for (int off = 8; off >= 1; off >>= 1) {
        r0 += __shfl_xor(r0, off);
        r1 += __shfl_xor(r1, off);
        r2 += __shfl_xor(r2, off);
        r3 += __shfl_xor(r3, off);
      }
      if (i == 0) {
        float* dst = (grp == 0 ? Qv : Kv) + (size_t)pos*4;
        dst[0]=r0; dst[1]=r1; dst[2]=r2; dst[3]=r3;
      }
    }
  }
}

// ---------------- Kernel Epre: pre-tile E into swizzled bf16 hi/lo tiles ----------------
// Tile (b, hb, tc) = [128 h][32 t], stored contiguous 4096 shorts (8 KB), in the
// exact swizzled LDS image the attn kernel consumes: off = h2*32 + (q2^((h2>>1)&3))*8.
__global__ __launch_bounds__(256) void epre_kernel(
    const float* __restrict__ E, unsigned short* __restrict__ EhiT,
    unsigned short* __restrict__ EloT) {
  int tc = blockIdx.x, hb = blockIdx.y, b = blockIdx.z;
  size_t tbase = ((size_t)((b*6 + hb)*64 + tc)) * 4096;
  const float* Eb = E + (size_t)b*NS*NH + (size_t)tc*32*NH + hb*128;
  int tid = threadIdx.x;
#pragma unroll
  for (int u = 0; u < 2; u++) {
    int unit = tid + 256*u;
    int h2 = unit & 127, q2 = unit >> 7;
    unsigned hi4[4], lo4[4];
#pragma unroll
    for (int jp = 0; jp < 4; jp++) {
      float ea = Eb[(size_t)(q2*8 + 2*jp    )*NH + h2];
      float eb = Eb[(size_t)(q2*8 + 2*jp + 1)*NH + h2];
      unsigned ba = __float_as_uint(ea), bb = __float_as_uint(eb);
      float la = ea - __uint_as_float(ba & 0xFFFF0000u);
      float lb = eb - __uint_as_float(bb & 0xFFFF0000u);
      hi4[jp] = pack_bf16(ba, bb);
      lo4[jp] = pack_bf16(__float_as_uint(la), __float_as_uint(lb));
    }
    int off = h2*32 + ((q2 ^ ((h2>>1)&3))*8);
    *(uint4*)&EhiT[tbase + off] = make_uint4(hi4[0],hi4[1],hi4[2],hi4[3]);
    *(uint4*)&EloT[tbase + off] = make_uint4(lo4[0],lo4[1],lo4[2],lo4[3]);
  }
}

// ---------------- Kernel C: fused flash attention, split-bf16 MFMA ----------------
// 128 s x 128 h per block, K-chunks of 32 t. B tiles DMA'd (global_load_lds,
// double-buffered, pre-swizzled). P-gen: q = waveId -> kvf reads are pure
// wave-broadcast (conflict-free); A-tile writes XOR-swizzled.
#define BS 128
#define BH 128
#define TK 32

__global__ __launch_bounds__(256, 3) void attn_kernel(
    const float* __restrict__ E, const float* __restrict__ Qv,
    const float* __restrict__ Kv, const unsigned short* __restrict__ EhiT,
    const unsigned short* __restrict__ EloT, float* __restrict__ out) {
  int sblk = blockIdx.x;   // 0..15
  int hblk = blockIdx.y;   // 0..5
  int b    = blockIdx.z;   // 0..7
  int tid  = threadIdx.x;
  int lane = tid & 63;
  int w    = tid >> 6;

  __shared__ __align__(16) unsigned short sAhi[BS*TK];
  __shared__ __align__(16) unsigned short sAlo[BS*TK];
  __shared__ __align__(16) unsigned short sBhi[2][BH*TK];
  __shared__ __align__(16) unsigned short sBlo[2][BH*TK];
  __shared__ __align__(16) float kvf[2][TK][4];
  __shared__ float denp[BS*4];
  __shared__ float dfin[BS];

  const float* Kvb = Kv + (size_t)b*NS*4;
  const unsigned short* tHi = EhiT + ((size_t)(b*6 + hblk)*64) * 4096;
  const unsigned short* tLo = EloT + ((size_t)(b*6 + hblk)*64) * 4096;

  // P-gen mapping: q = wave id (kvf rows wave-uniform -> broadcast reads),
  // s = lane (+64 for second half)
  int qw = w, sL = lane;
  floatx4 qv0, qv1;
  {
    const float4 t0 = *(const float4*)&Qv[((size_t)(b*NS + sblk*BS) + sL)*4];
    const float4 t1 = *(const float4*)&Qv[((size_t)(b*NS + sblk*BS) + 64 + sL)*4];
    qv0 = floatx4{t0.x, t0.y, t0.z, t0.w};
    qv1 = floatx4{t1.x, t1.y, t1.z, t1.w};
  }
  float den0 = 0.f, den1 = 0.f;

  int sh = w & 1, hh = w >> 1;
  floatx4 acc[4][4];
#pragma unroll
  for (int i = 0; i < 4; i++)
#pragma unroll
    for (int jt = 0; jt < 4; jt++) acc[i][jt] = floatx4{0.f,0.f,0.f,0.f};

  int m16 = lane & 15, q16 = lane >> 4;
  int cidx = (q16 ^ ((m16 >> 1) & 3)) * 8;   // swizzled chunk offset for frag reads

  // prologue: DMA chunk 0 (B tiles + kv)
  GLOAD_LDS16(tHi + (size_t)tid*8,        &sBhi[0][tid*8]);
  GLOAD_LDS16(tHi + 2048 + (size_t)tid*8, &sBhi[0][2048 + tid*8]);
  GLOAD_LDS16(tLo + (size_t)tid*8,        &sBlo[0][tid*8]);
  GLOAD_LDS16(tLo + 2048 + (size_t)tid*8, &sBlo[0][2048 + tid*8]);
  if (tid < 32) GLOAD_LDS16(Kvb + tid*4, &kvf[0][0][0] + tid*4);

  for (int tc = 0; tc < NS; tc += TK) {
    int cb = (tc >> 5) & 1;
    __syncthreads();   // drains DMA for chunk tc; prev MFMA done reading sA

    // --- P-gen: p = exp(qv.kv); kvf reads are wave-broadcast ---
    {
      unsigned hiA[2][4], loA[2][4];
#pragma unroll
      for (int jp = 0; jp < 4; jp++) {
        float4 ka = *(const float4*)&kvf[cb][qw*8 + 2*jp][0];
        float4 kb = *(const float4*)&kvf[cb][qw*8 + 2*jp + 1][0];
#pragma unroll
        for (int r = 0; r < 2; r++) {
          floatx4 qv = r ? qv1 : qv0;
          float arga = qv.x*ka.x + qv.y*ka.y + qv.z*ka.z + qv.w*ka.w;
          float argb = qv.x*kb.x + qv.y*kb.y + qv.z*kb.z + qv.w*kb.w;
          float pa = __expf(arga), pb = __expf(argb);
          if (r) den1 += pa + pb; else den0 += pa + pb;
          unsigned bpa = __float_as_uint(pa), bpb = __float_as_uint(pb);
          float lpa = pa - __uint_as_float(bpa & 0xFFFF0000u);
          float lpb = pb - __uint_as_float(bpb & 0xFFFF0000u);
          hiA[r][jp] = pack_bf16(bpa, bpb);
          loA[r][jp] = pack_bf16(__float_as_uint(lpa), __float_as_uint(lpb));
        }
      }
#pragma unroll
      for (int r = 0; r < 2; r++) {
        int s = sL + 64*r;
        int off = s*TK + ((qw ^ ((s>>1)&3))*8);
        *(uint4*)&sAhi[off] = make_uint4(hiA[r][0],hiA[r][1],hiA[r][2],hiA[r][3]);
        *(uint4*)&sAlo[off] = make_uint4(loA[r][0],loA[r][1],loA[r][2],loA[r][3]);
      }
    }

    __syncthreads();   // sA ready (sB[cb], kvf[cb] were ready at top barrier)

    // --- issue DMA for next chunk (drains at next top barrier, behind MFMA) ---
    if (tc + TK < NS) {
      int nb = cb ^ 1;
      const unsigned short* nHi = tHi + (size_t)((tc >> 5) + 1) * 4096;
      const unsigned short* nLo = tLo + (size_t)((tc >> 5) + 1) * 4096;
      GLOAD_LDS16(nHi + (size_t)tid*8,        &sBhi[nb][tid*8]);
      GLOAD_LDS16(nHi + 2048 + (size_t)tid*8, &sBhi[nb][2048 + tid*8]);
      GLOAD_LDS16(nLo + (size_t)tid*8,        &sBlo[nb][tid*8]);
      GLOAD_LDS16(nLo + 2048 + (size_t)tid*8, &sBlo[nb][2048 + tid*8]);
      if (tid < 32) GLOAD_LDS16(Kvb + (size_t)(tc+TK)*4 + tid*4, &kvf[nb][0][0] + tid*4);
    }

    // --- MFMA: wave (sh,hh) computes 64x64 via 4x4 tiles of 16x16x32, 3 passes ---
    short8 bh_[4], bl_[4];
#pragma unroll
    for (int jt = 0; jt < 4; jt++) {
      int hrow = hh*64 + jt*16 + m16;
      bh_[jt] = __builtin_bit_cast(short8, *(const uint4*)&sBhi[cb][hrow*TK + cidx]);
      bl_[jt] = __builtin_bit_cast(short8, *(const uint4*)&sBlo[cb][hrow*TK + cidx]);
    }
#pragma unroll
    for (int i = 0; i < 4; i++) {
      int srow = sh*64 + i*16 + m16;
      short8 ah = __builtin_bit_cast(short8, *(const uint4*)&sAhi[srow*TK + cidx]);
      short8 al = __builtin_bit_cast(short8, *(const uint4*)&sAlo[srow*TK + cidx]);
#pragma unroll
      for (int jt = 0; jt < 4; jt++) {
        acc[i][jt] = __builtin_amdgcn_mfma_f32_16x16x32_bf16(ah, bl_[jt], acc[i][jt], 0, 0, 0);
        acc[i][jt] = __builtin_amdgcn_mfma_f32_16x16x32_bf16(al, bh_[jt], acc[i][jt], 0, 0, 0);
        acc[i][jt] = __builtin_amdgcn_mfma_f32_16x16x32_bf16(ah, bh_[jt], acc[i][jt], 0, 0, 0);
      }
    }
  }

  // --- denominator reduce ---
  __syncthreads();
  denp[sL*4 + qw] = den0;
  denp[(64 + sL)*4 + qw] = den1;
  __syncthreads();
  if (tid < BS) {
    dfin[tid] = denp[tid*4] + denp[tid*4+1] + denp[tid*4+2] + denp[tid*4+3];
  }
  __syncthreads();

  // --- epilogue: C/D layout col=lane&15, row=(lane>>4)*4+reg ---
  float* ob = out + ((size_t)(b*NS + sblk*BS))*NH + hblk*BH;
#pragma unroll
  for (int i = 0; i < 4; i++) {
#pragma unroll
    for (int reg = 0; reg < 4; reg++) {
      int row = q16*4 + reg;
      int s_loc = sh*64 + i*16 + row;
      float invd = 1.0f / dfin[s_loc];
#pragma unroll
      for (int jt = 0; jt < 4; jt++) {
        int h_loc = hh*64 + jt*16 + m16;
        ob[(size_t)s_loc*NH + h_loc] = acc[i][jt][reg] * invd;
      }
    }
  }
}

extern "C" void kernel_launch(void* const* d_in, const int* in_sizes, int n_in,
                              void* d_out, int out_size, void* d_ws, size_t ws_size,
                              hipStream_t stream) {
  const float* E   = (const float*)d_in[0];
  const float* Wq  = (const float*)d_in[1];
  const float* bq  = (const float*)d_in[2];
  const float* Wk  = (const float*)d_in[3];
  const float* bk  = (const float*)d_in[4];
  const float* wts = (const float*)d_in[5];
  float* ws  = (float*)d_ws;
  float* Vre = ws;
  float* Vim = ws + 256;
  float* Qv  = ws + 512;
  float* Kv  = ws + 512 + NPOS*4;
  unsigned short* EhiT = (unsigned short*)(ws + 512 + 2*NPOS*4);
  unsigned short* EloT = EhiT + (size_t)NB*6*64*4096;   // ~51 MB total ws use
  float* out = (float*)d_out;

  build_V_kernel<<<1, 64, 0, stream>>>(wts, Vre, Vim);
  epre_kernel<<<dim3(64, 6, 8), 256, 0, stream>>>(E, EhiT, EloT);
  proj_vqc_kernel<<<1024, 256, 0, stream>>>(E, Wq, bq, Wk, bk, Vre, Vim, Qv, Kv);
  attn_kernel<<<dim3(16, 6, 8), 256, 0, stream>>>(E, Qv, Kv, EhiT, EloT, out);
}